// Round 6
// baseline (19408.952 us; speedup 1.0000x reference)
//
#include <hip/hip_runtime.h>

#define B_ 128
#define T_ 200
#define INF_ 175
#define INFP_ 192
#define H_ 1024
#define G4_ 4096
#define OUTF_ 175
#define BH3_ (3 * B_ * H_)
#define NCELL 192
#define NDEC 22
#define NBLK (NCELL + NDEC)

typedef __bf16 bf16x8 __attribute__((ext_vector_type(8)));
typedef float f32x4 __attribute__((ext_vector_type(4)));

// ---- persistent device state ----
__device__ __attribute__((aligned(16))) __bf16 g_Wih1p[G4_ * INFP_];
__device__ __attribute__((aligned(16))) __bf16 g_Whh1[G4_ * H_];
__device__ __attribute__((aligned(16))) __bf16 g_Wih2[G4_ * H_];
__device__ __attribute__((aligned(16))) __bf16 g_Whh2[G4_ * H_];
__device__ __attribute__((aligned(16))) __bf16 g_Wih3[G4_ * H_];
__device__ __attribute__((aligned(16))) __bf16 g_Whh3[G4_ * H_];
__device__ __attribute__((aligned(16))) __bf16 g_Wdec[OUTF_ * H_];
__device__ float g_bsum[3 * G4_];
__device__ float g_bdec[OUTF_];
__device__ __attribute__((aligned(16))) __bf16 g_h[2][BH3_];
__device__ __attribute__((aligned(16))) __bf16 g_infp[B_ * INFP_];
__device__ int g_isf32;
__device__ int g_cnt;
__device__ int g_gen;
__device__ int g_dflag;

__device__ __forceinline__ f32x4 mfma_bf16(bf16x8 a, bf16x8 b, f32x4 c) {
    return __builtin_amdgcn_mfma_f32_16x16x32_bf16(a, b, c, 0, 0, 0);
}
__device__ __forceinline__ bf16x8 ld8(const __bf16* p) {
    return *reinterpret_cast<const bf16x8*>(p);
}
__device__ __forceinline__ float sigm(float x) { return 1.f / (1.f + expf(-x)); }
__device__ __forceinline__ float rdf(const void* p, long i, int f32) {
    return f32 ? ((const float*)p)[i] : (float)((const __bf16*)p)[i];
}

// bounded spin: RELAXED polls (no per-poll L2 invalidate!), one ACQUIRE at exit.
__device__ __forceinline__ void spinwait(int* addr, int target) {
    for (int it = 0; it < 500000; ++it) {
        if (__hip_atomic_load(addr, __ATOMIC_RELAXED, __HIP_MEMORY_SCOPE_AGENT) >= target)
            break;
        __builtin_amdgcn_s_sleep(4);
    }
    (void)__hip_atomic_load(addr, __ATOMIC_ACQUIRE, __HIP_MEMORY_SCOPE_AGENT);
}

// ---- dtype probe ----
__global__ void detect_k(const unsigned int* __restrict__ xw) {
    __shared__ int cnt;
    if (threadIdx.x == 0) cnt = 0;
    __syncthreads();
    unsigned int w = xw[threadIdx.x];
    int e = (w >> 7) & 0xFF;
    if (e >= 140) atomicAdd(&cnt, 1);
    __syncthreads();
    if (threadIdx.x == 0) g_isf32 = (cnt >= 16) ? 1 : 0;
}

// ---- prep ----
__global__ void prep_k(const void* Wih1, const void* Whh1, const void* Wih2,
                       const void* Whh2, const void* Wih3, const void* Whh3,
                       const void* Wdec, const void* bih1, const void* bhh1,
                       const void* bih2, const void* bhh2, const void* bih3,
                       const void* bhh3, const void* bdec, const void* xseq) {
    const int f = g_isf32;
    const int idx = blockIdx.x * 256 + threadIdx.x;
    const int stride = gridDim.x * 256;
    if (idx == 0) { g_cnt = 0; g_gen = 0; g_dflag = 0; }
    for (int i = idx; i < G4_ * INFP_; i += stride) {
        int n = i / INFP_, k = i - n * INFP_;
        g_Wih1p[i] = (k < INF_) ? (__bf16)rdf(Wih1, (long)n * INF_ + k, f) : (__bf16)0.f;
    }
    for (int i = idx; i < G4_ * H_; i += stride) {
        g_Whh1[i] = (__bf16)rdf(Whh1, i, f);
        g_Wih2[i] = (__bf16)rdf(Wih2, i, f);
        g_Whh2[i] = (__bf16)rdf(Whh2, i, f);
        g_Wih3[i] = (__bf16)rdf(Wih3, i, f);
        g_Whh3[i] = (__bf16)rdf(Whh3, i, f);
    }
    for (int i = idx; i < OUTF_ * H_; i += stride) g_Wdec[i] = (__bf16)rdf(Wdec, i, f);
    for (int i = idx; i < G4_; i += stride) {
        g_bsum[i]           = rdf(bih1, i, f) + rdf(bhh1, i, f);
        g_bsum[G4_ + i]     = rdf(bih2, i, f) + rdf(bhh2, i, f);
        g_bsum[2 * G4_ + i] = rdf(bih3, i, f) + rdf(bhh3, i, f);
    }
    for (int i = idx; i < OUTF_; i += stride) g_bdec[i] = rdf(bdec, i, f);
    for (int i = idx; i < 2 * BH3_; i += stride) (&g_h[0][0])[i] = (__bf16)0.f;
    for (int i = idx; i < B_ * INFP_; i += stride) {
        int b = i / INFP_, k = i - b * INFP_;
        g_infp[i] = (k < INF_) ? (__bf16)rdf(xseq, (long)b * (T_ * INF_) + k, f) : (__bf16)0.f;
    }
}

// ---- grid barrier (214 blocks, 1/CU guaranteed) ----
__device__ __forceinline__ void gridbar(int target) {
    __syncthreads();
    if (threadIdx.x == 0) {
        __threadfence();
        int v = __hip_atomic_fetch_add(&g_cnt, 1, __ATOMIC_ACQ_REL, __HIP_MEMORY_SCOPE_AGENT);
        if (v == NBLK - 1) {
            __hip_atomic_store(&g_cnt, 0, __ATOMIC_RELAXED, __HIP_MEMORY_SCOPE_AGENT);
            __hip_atomic_store(&g_gen, target, __ATOMIC_RELEASE, __HIP_MEMORY_SCOPE_AGENT);
        } else {
            spinwait(&g_gen, target);
        }
    }
    __syncthreads();
}

// depth-2 register-pipelined GEMM over NCH k-chunks (32 elems each); weights
// are resident in wreg[] for the whole kernel. All indices compile-time.
template <int NCH>
__device__ __forceinline__ void gemm_op(const __bf16* const (&ap)[8],
                                        const bf16x8 (&wreg)[32],
                                        f32x4 (&acc)[8]) {
    bf16x8 a0[8], a1[8];
#pragma unroll
    for (int mf = 0; mf < 8; ++mf) a0[mf] = ld8(ap[mf]);
    if (NCH > 1) {
#pragma unroll
        for (int mf = 0; mf < 8; ++mf) a1[mf] = ld8(ap[mf] + 32);
    }
#pragma unroll
    for (int c = 0; c < NCH; c += 2) {
#pragma unroll
        for (int mf = 0; mf < 8; ++mf)
            acc[mf] = mfma_bf16(a0[mf], wreg[c], acc[mf]);
        if (c + 2 < NCH) {
#pragma unroll
            for (int mf = 0; mf < 8; ++mf) a0[mf] = ld8(ap[mf] + (c + 2) * 32);
        }
        if (c + 1 < NCH) {
#pragma unroll
            for (int mf = 0; mf < 8; ++mf)
                acc[mf] = mfma_bf16(a1[mf], wreg[c + 1], acc[mf]);
            if (c + 3 < NCH) {
#pragma unroll
                for (int mf = 0; mf < 8; ++mf) a1[mf] = ld8(ap[mf] + (c + 3) * 32);
            }
        }
    }
}

// ---- persistent kernel: weights register-stationary, 1 barrier/step ----
__global__ __launch_bounds__(512, 2) void persist_k(const void* __restrict__ xseq,
                                                    void* __restrict__ dout) {
    __shared__ float s_acc[B_ * 4 * 16];  // 32KB [row128][gate4][col16]
    __shared__ float s_c[B_ * 16];        // 8KB
    const int bid = blockIdx.x;
    const int tid = threadIdx.x;
    const int lane = tid & 63;
    const int wid = tid >> 6;            // 0..7
    const int rlo = lane & 15, khi = lane >> 4;
    const int f32o = g_isf32;

    if (bid < NCELL) {
        // ================= CELL BLOCK =================
        const int L = bid >> 6;
        const int hc0 = (bid & 63) << 4;
        const int op = wid >> 2;         // 0: x-operand GEMM, 1: recurrent GEMM
        const int g = wid & 3;           // gate = n-frag
        const float* bs = g_bsum + L * G4_;

        // ---- preload this wave's weight tile into registers (held 200 steps) ----
        const __bf16* Bm; int K;
        if (op == 0) {
            if (L == 0) { Bm = g_Wih1p; K = INFP_; }
            else        { Bm = (L == 1) ? g_Wih2 : g_Wih3; K = H_; }
        } else {
            Bm = (L == 0) ? g_Whh1 : (L == 1) ? g_Whh2 : g_Whh3; K = H_;
        }
        const __bf16* wp = Bm + (long)(g * H_ + hc0 + rlo) * K + khi * 8;
        bf16x8 wreg[32];
        if (K == INFP_) {
#pragma unroll
            for (int c = 0; c < 6; ++c) wreg[c] = ld8(wp + c * 32);
        } else {
#pragma unroll
            for (int c = 0; c < 32; ++c) wreg[c] = ld8(wp + c * 32);
        }

        for (int i = tid; i < B_ * 16; i += 512) s_c[i] = 0.f;

        for (int p = 0; p < T_; ++p) {
            const __bf16* hin = g_h[p & 1];
            const __bf16* Ap; int sA;
            if (op == 0) {
                if (L == 0) { Ap = g_infp; sA = INFP_; }
                else        { Ap = hin + (L - 1) * B_ * H_; sA = H_; }
            } else { Ap = hin + L * B_ * H_; sA = H_; }

            // L0 x-waves wait for this step's in_frame (dec blocks, skewed)
            if (L == 0 && op == 0 && p > 0) {
                if (lane == 0) spinwait(&g_dflag, NDEC * p);
            }

            const __bf16* ap[8];
#pragma unroll
            for (int mf = 0; mf < 8; ++mf)
                ap[mf] = Ap + (mf * 16 + rlo) * sA + khi * 8;

            f32x4 acc[8] = {};
            if (K == INFP_) gemm_op<6>(ap, wreg, acc);
            else            gemm_op<32>(ap, wreg, acc);

            // operand-split reduce through LDS
            if (op == 1) {
#pragma unroll
                for (int mf = 0; mf < 8; ++mf)
#pragma unroll
                    for (int j = 0; j < 4; ++j) {
                        int r = mf * 16 + khi * 4 + j;
                        s_acc[(r * 4 + g) * 16 + rlo] = acc[mf][j];
                    }
            }
            __syncthreads();
            if (op == 0) {
#pragma unroll
                for (int mf = 0; mf < 8; ++mf)
#pragma unroll
                    for (int j = 0; j < 4; ++j) {
                        int r = mf * 16 + khi * 4 + j;
                        s_acc[(r * 4 + g) * 16 + rlo] += acc[mf][j];
                    }
            }
            __syncthreads();

            // epilogue: 8 waves x 16 rows, 4 cols/lane
            {
                const int r = wid * 16 + rlo;
                const int hq = khi;
                f32x4 ga = *(const f32x4*)&s_acc[(r * 4 + 0) * 16 + hq * 4];
                f32x4 gf = *(const f32x4*)&s_acc[(r * 4 + 1) * 16 + hq * 4];
                f32x4 gg = *(const f32x4*)&s_acc[(r * 4 + 2) * 16 + hq * 4];
                f32x4 go = *(const f32x4*)&s_acc[(r * 4 + 3) * 16 + hq * 4];
                f32x4 cv = *(const f32x4*)&s_c[r * 16 + hq * 4];
                __bf16 hv[4];
#pragma unroll
                for (int e = 0; e < 4; ++e) {
                    int col = hc0 + hq * 4 + e;
                    float gi_ = ga[e] + bs[0 * H_ + col];
                    float gf_ = gf[e] + bs[1 * H_ + col];
                    float gg_ = gg[e] + bs[2 * H_ + col];
                    float go_ = go[e] + bs[3 * H_ + col];
                    float cn = sigm(gf_) * cv[e] + sigm(gi_) * tanhf(gg_);
                    cv[e] = cn;
                    hv[e] = (__bf16)(sigm(go_) * tanhf(cn));
                }
                *(f32x4*)&s_c[r * 16 + hq * 4] = cv;
                __bf16* hdst = g_h[(p + 1) & 1] + L * B_ * H_ + r * H_ + hc0 + hq * 4;
                *(uint2*)hdst = *(const uint2*)hv;
            }
            gridbar(p + 1);
        }
    } else {
        // ================= DEC BLOCK =================
        const int db = bid - NCELL;
        const int ntile = db % 11, mh = db / 11;
        const int kk = wid >> 2;
        const int mw = wid & 3;
        const int col = ntile * 16 + rlo;
        const int colc = (col < OUTF_) ? col : (OUTF_ - 1);

        auto decwork = [&](int t, bool winf) {
            const __bf16* h2 = g_h[(t + 1) & 1] + 2 * B_ * H_;
            const __bf16* pa = h2 + (mh * 64 + mw * 16 + rlo) * H_ + kk * 512 + khi * 8;
            const __bf16* pb = g_Wdec + (long)colc * H_ + kk * 512 + khi * 8;
            f32x4 acc = {};
            bf16x8 a0, a1, b0, b1, c0, c1, d0, d1;
            a0 = ld8(pa); a1 = ld8(pa + 32); b0 = ld8(pb); b1 = ld8(pb + 32);
            c0 = ld8(pa + 64); c1 = ld8(pa + 96); d0 = ld8(pb + 64); d1 = ld8(pb + 96);
            for (int i = 0; i < 8; i += 2) {
                acc = mfma_bf16(a0, b0, acc);
                acc = mfma_bf16(a1, b1, acc);
                if (i + 2 < 8) {
                    int k = (i + 2) << 6;
                    a0 = ld8(pa + k); a1 = ld8(pa + k + 32);
                    b0 = ld8(pb + k); b1 = ld8(pb + k + 32);
                }
                acc = mfma_bf16(c0, d0, acc);
                acc = mfma_bf16(c1, d1, acc);
                if (i + 3 < 8) {
                    int k = (i + 3) << 6;
                    c0 = ld8(pa + k); c1 = ld8(pa + k + 32);
                    d0 = ld8(pb + k); d1 = ld8(pb + k + 32);
                }
            }
            if (kk == 1) {
#pragma unroll
                for (int j = 0; j < 4; ++j)
                    s_acc[(mw * 16 + khi * 4 + j) * 16 + rlo] = acc[j];
            }
            __syncthreads();
            if (kk == 0) {
#pragma unroll
                for (int j = 0; j < 4; ++j)
                    acc[j] += s_acc[(mw * 16 + khi * 4 + j) * 16 + rlo];
                if (col < OUTF_) {
                    const float bias = g_bdec[col];
                    const bool gt = (((t + 1) % 10) < 5);
#pragma unroll
                    for (int j = 0; j < 4; ++j) {
                        int row = mh * 64 + mw * 16 + khi * 4 + j;
                        float ov = acc[j] + bias;
                        long oidx = (long)row * (T_ * OUTF_) + (long)t * OUTF_ + col;
                        if (f32o) ((float*)dout)[oidx] = ov;
                        else ((__bf16*)dout)[oidx] = (__bf16)ov;
                        if (winf) {
                            float nxt = gt ? rdf(xseq, (long)row * (T_ * INF_) + (long)(t + 1) * INF_ + col, f32o)
                                           : ov;
                            g_infp[row * INFP_ + col] = (__bf16)nxt;
                        }
                    }
                }
            }
            __syncthreads();
            if (tid == 0) {
                __threadfence();
                __hip_atomic_fetch_add(&g_dflag, 1, __ATOMIC_RELEASE, __HIP_MEMORY_SCOPE_AGENT);
            }
        };

        for (int p = 0; p < T_; ++p) {
            if (p >= 1) decwork(p - 1, true);
            gridbar(p + 1);
        }
        decwork(T_ - 1, false);
    }
}

extern "C" void kernel_launch(void* const* d_in, const int* in_sizes, int n_in,
                              void* d_out, int out_size, void* d_ws, size_t ws_size,
                              hipStream_t stream) {
    const void* xseq = d_in[0];
    detect_k<<<1, 256, 0, stream>>>((const unsigned int*)xseq);
    prep_k<<<2048, 256, 0, stream>>>(d_in[1], d_in[2], d_in[5], d_in[6], d_in[9],
                                     d_in[10], d_in[13], d_in[3], d_in[4], d_in[7],
                                     d_in[8], d_in[11], d_in[12], d_in[14], xseq);
    persist_k<<<NBLK, 512, 0, stream>>>(xseq, d_out);
}

// Round 7
// 17756.427 us; speedup vs baseline: 1.0931x; 1.0931x over previous
//
#include <hip/hip_runtime.h>

#define B_ 128
#define T_ 200
#define INF_ 175
#define INFP_ 192
#define H_ 1024
#define G4_ 4096
#define OUTF_ 175
#define BH3_ (3 * B_ * H_)
#define NCELL 192
#define NDEC 22
#define NBLK (NCELL + NDEC)

typedef __bf16 bf16x8 __attribute__((ext_vector_type(8)));
typedef float f32x4 __attribute__((ext_vector_type(4)));

// ---- persistent device state ----
__device__ __attribute__((aligned(16))) __bf16 g_Wih1p[G4_ * INFP_];
__device__ __attribute__((aligned(16))) __bf16 g_Whh1[G4_ * H_];
__device__ __attribute__((aligned(16))) __bf16 g_Wih2[G4_ * H_];
__device__ __attribute__((aligned(16))) __bf16 g_Whh2[G4_ * H_];
__device__ __attribute__((aligned(16))) __bf16 g_Wih3[G4_ * H_];
__device__ __attribute__((aligned(16))) __bf16 g_Whh3[G4_ * H_];
__device__ __attribute__((aligned(16))) __bf16 g_Wdec[OUTF_ * H_];
__device__ float g_bsum[3 * G4_];
__device__ float g_bdec[OUTF_];
__device__ __attribute__((aligned(16))) __bf16 g_h[2][BH3_];
__device__ __attribute__((aligned(16))) __bf16 g_infp[B_ * INFP_];
__device__ int g_isf32;
__device__ int g_cnt;
__device__ int g_gen;
__device__ int g_dflag;

__device__ __forceinline__ f32x4 mfma_bf16(bf16x8 a, bf16x8 b, f32x4 c) {
    return __builtin_amdgcn_mfma_f32_16x16x32_bf16(a, b, c, 0, 0, 0);
}
__device__ __forceinline__ bf16x8 ld8(const __bf16* p) {
    return *reinterpret_cast<const bf16x8*>(p);
}
__device__ __forceinline__ float sigm(float x) { return 1.f / (1.f + expf(-x)); }
__device__ __forceinline__ float rdf(const void* p, long i, int f32) {
    return f32 ? ((const float*)p)[i] : (float)((const __bf16*)p)[i];
}

// bounded spin: RELAXED polls, one ACQUIRE at exit; bound converts any
// deadlock into a finite garbage-result failure instead of a dead container.
__device__ __forceinline__ void spinwait(int* addr, int target) {
    for (int it = 0; it < 500000; ++it) {
        if (__hip_atomic_load(addr, __ATOMIC_RELAXED, __HIP_MEMORY_SCOPE_AGENT) >= target)
            break;
        __builtin_amdgcn_s_sleep(4);
    }
    (void)__hip_atomic_load(addr, __ATOMIC_ACQUIRE, __HIP_MEMORY_SCOPE_AGENT);
}

// ---- dtype probe ----
__global__ void detect_k(const unsigned int* __restrict__ xw) {
    __shared__ int cnt;
    if (threadIdx.x == 0) cnt = 0;
    __syncthreads();
    unsigned int w = xw[threadIdx.x];
    int e = (w >> 7) & 0xFF;
    if (e >= 140) atomicAdd(&cnt, 1);
    __syncthreads();
    if (threadIdx.x == 0) g_isf32 = (cnt >= 16) ? 1 : 0;
}

// ---- prep ----
__global__ void prep_k(const void* Wih1, const void* Whh1, const void* Wih2,
                       const void* Whh2, const void* Wih3, const void* Whh3,
                       const void* Wdec, const void* bih1, const void* bhh1,
                       const void* bih2, const void* bhh2, const void* bih3,
                       const void* bhh3, const void* bdec, const void* xseq) {
    const int f = g_isf32;
    const int idx = blockIdx.x * 256 + threadIdx.x;
    const int stride = gridDim.x * 256;
    if (idx == 0) { g_cnt = 0; g_gen = 0; g_dflag = 0; }
    for (int i = idx; i < G4_ * INFP_; i += stride) {
        int n = i / INFP_, k = i - n * INFP_;
        g_Wih1p[i] = (k < INF_) ? (__bf16)rdf(Wih1, (long)n * INF_ + k, f) : (__bf16)0.f;
    }
    for (int i = idx; i < G4_ * H_; i += stride) {
        g_Whh1[i] = (__bf16)rdf(Whh1, i, f);
        g_Wih2[i] = (__bf16)rdf(Wih2, i, f);
        g_Whh2[i] = (__bf16)rdf(Whh2, i, f);
        g_Wih3[i] = (__bf16)rdf(Wih3, i, f);
        g_Whh3[i] = (__bf16)rdf(Whh3, i, f);
    }
    for (int i = idx; i < OUTF_ * H_; i += stride) g_Wdec[i] = (__bf16)rdf(Wdec, i, f);
    for (int i = idx; i < G4_; i += stride) {
        g_bsum[i]           = rdf(bih1, i, f) + rdf(bhh1, i, f);
        g_bsum[G4_ + i]     = rdf(bih2, i, f) + rdf(bhh2, i, f);
        g_bsum[2 * G4_ + i] = rdf(bih3, i, f) + rdf(bhh3, i, f);
    }
    for (int i = idx; i < OUTF_; i += stride) g_bdec[i] = rdf(bdec, i, f);
    for (int i = idx; i < 2 * BH3_; i += stride) (&g_h[0][0])[i] = (__bf16)0.f;
    for (int i = idx; i < B_ * INFP_; i += stride) {
        int b = i / INFP_, k = i - b * INFP_;
        g_infp[i] = (k < INF_) ? (__bf16)rdf(xseq, (long)b * (T_ * INF_) + k, f) : (__bf16)0.f;
    }
}

// ---- grid barrier (214 blocks, 1 block/CU guaranteed at launch_bounds(512,1)) ----
__device__ __forceinline__ void gridbar(int target) {
    __syncthreads();
    if (threadIdx.x == 0) {
        __threadfence();
        int v = __hip_atomic_fetch_add(&g_cnt, 1, __ATOMIC_ACQ_REL, __HIP_MEMORY_SCOPE_AGENT);
        if (v == NBLK - 1) {
            __hip_atomic_store(&g_cnt, 0, __ATOMIC_RELAXED, __HIP_MEMORY_SCOPE_AGENT);
            __hip_atomic_store(&g_gen, target, __ATOMIC_RELEASE, __HIP_MEMORY_SCOPE_AGENT);
        } else {
            spinwait(&g_gen, target);
        }
    }
    __syncthreads();
}

// depth-2 register-pipelined GEMM over NCH k-chunks for m-frags [BASE,BASE+4);
// weights stay resident in wreg[]. BASE is compile-time so acc stays in regs.
template <int NCH, int BASE>
__device__ __forceinline__ void gemm_half(const __bf16* const (&ap)[8],
                                          const bf16x8 (&wreg)[32],
                                          f32x4 (&acc)[8]) {
    bf16x8 a0[4], a1[4];
#pragma unroll
    for (int mf = 0; mf < 4; ++mf) a0[mf] = ld8(ap[BASE + mf]);
    if (NCH > 1) {
#pragma unroll
        for (int mf = 0; mf < 4; ++mf) a1[mf] = ld8(ap[BASE + mf] + 32);
    }
#pragma unroll
    for (int c = 0; c < NCH; c += 2) {
#pragma unroll
        for (int mf = 0; mf < 4; ++mf)
            acc[BASE + mf] = mfma_bf16(a0[mf], wreg[c], acc[BASE + mf]);
        if (c + 2 < NCH) {
#pragma unroll
            for (int mf = 0; mf < 4; ++mf) a0[mf] = ld8(ap[BASE + mf] + (c + 2) * 32);
        }
        if (c + 1 < NCH) {
#pragma unroll
            for (int mf = 0; mf < 4; ++mf)
                acc[BASE + mf] = mfma_bf16(a1[mf], wreg[c + 1], acc[BASE + mf]);
            if (c + 3 < NCH) {
#pragma unroll
                for (int mf = 0; mf < 4; ++mf) a1[mf] = ld8(ap[BASE + mf] + (c + 3) * 32);
            }
        }
    }
}

// ---- persistent kernel: weights register-stationary, 1 barrier/step ----
// launch_bounds(512, 1): 1 block/CU -> 2 waves/SIMD -> 256-VGPR budget.
// (512, 2) capped VGPR at 128 and spilled the whole wreg tile (round 6).
__global__ __launch_bounds__(512, 1) void persist_k(const void* __restrict__ xseq,
                                                    void* __restrict__ dout) {
    __shared__ float s_acc[B_ * 4 * 16];  // 32KB [row128][gate4][col16]
    __shared__ float s_c[B_ * 16];        // 8KB
    const int bid = blockIdx.x;
    const int tid = threadIdx.x;
    const int lane = tid & 63;
    const int wid = tid >> 6;            // 0..7
    const int rlo = lane & 15, khi = lane >> 4;
    const int f32o = g_isf32;

    if (bid < NCELL) {
        // ================= CELL BLOCK =================
        const int L = bid >> 6;
        const int hc0 = (bid & 63) << 4;
        const int op = wid >> 2;         // 0: x-operand GEMM, 1: recurrent GEMM
        const int g = wid & 3;           // gate = n-frag
        const float* bs = g_bsum + L * G4_;

        // ---- preload this wave's weight tile into registers (held 200 steps) ----
        const __bf16* Bm; int K;
        if (op == 0) {
            if (L == 0) { Bm = g_Wih1p; K = INFP_; }
            else        { Bm = (L == 1) ? g_Wih2 : g_Wih3; K = H_; }
        } else {
            Bm = (L == 0) ? g_Whh1 : (L == 1) ? g_Whh2 : g_Whh3; K = H_;
        }
        const __bf16* wp = Bm + (long)(g * H_ + hc0 + rlo) * K + khi * 8;
        bf16x8 wreg[32];
        if (K == INFP_) {
#pragma unroll
            for (int c = 0; c < 6; ++c) wreg[c] = ld8(wp + c * 32);
        } else {
#pragma unroll
            for (int c = 0; c < 32; ++c) wreg[c] = ld8(wp + c * 32);
        }

        for (int i = tid; i < B_ * 16; i += 512) s_c[i] = 0.f;

        for (int p = 0; p < T_; ++p) {
            const __bf16* hin = g_h[p & 1];
            const __bf16* Ap; int sA;
            if (op == 0) {
                if (L == 0) { Ap = g_infp; sA = INFP_; }
                else        { Ap = hin + (L - 1) * B_ * H_; sA = H_; }
            } else { Ap = hin + L * B_ * H_; sA = H_; }

            // L0 x-waves wait for this step's in_frame (dec blocks, skewed)
            if (L == 0 && op == 0 && p > 0) {
                if (lane == 0) spinwait(&g_dflag, NDEC * p);
            }

            const __bf16* ap[8];
#pragma unroll
            for (int mf = 0; mf < 8; ++mf)
                ap[mf] = Ap + (mf * 16 + rlo) * sA + khi * 8;

            f32x4 acc[8] = {};
            if (K == INFP_) {
                gemm_half<6, 0>(ap, wreg, acc);
                gemm_half<6, 4>(ap, wreg, acc);
            } else {
                gemm_half<32, 0>(ap, wreg, acc);
                gemm_half<32, 4>(ap, wreg, acc);
            }

            // operand-split reduce through LDS
            if (op == 1) {
#pragma unroll
                for (int mf = 0; mf < 8; ++mf)
#pragma unroll
                    for (int j = 0; j < 4; ++j) {
                        int r = mf * 16 + khi * 4 + j;
                        s_acc[(r * 4 + g) * 16 + rlo] = acc[mf][j];
                    }
            }
            __syncthreads();
            if (op == 0) {
#pragma unroll
                for (int mf = 0; mf < 8; ++mf)
#pragma unroll
                    for (int j = 0; j < 4; ++j) {
                        int r = mf * 16 + khi * 4 + j;
                        s_acc[(r * 4 + g) * 16 + rlo] += acc[mf][j];
                    }
            }
            __syncthreads();

            // epilogue: 8 waves x 16 rows, 4 cols/lane
            {
                const int r = wid * 16 + rlo;
                const int hq = khi;
                f32x4 ga = *(const f32x4*)&s_acc[(r * 4 + 0) * 16 + hq * 4];
                f32x4 gf = *(const f32x4*)&s_acc[(r * 4 + 1) * 16 + hq * 4];
                f32x4 gg = *(const f32x4*)&s_acc[(r * 4 + 2) * 16 + hq * 4];
                f32x4 go = *(const f32x4*)&s_acc[(r * 4 + 3) * 16 + hq * 4];
                f32x4 cv = *(const f32x4*)&s_c[r * 16 + hq * 4];
                __bf16 hv[4];
#pragma unroll
                for (int e = 0; e < 4; ++e) {
                    int col = hc0 + hq * 4 + e;
                    float gi_ = ga[e] + bs[0 * H_ + col];
                    float gf_ = gf[e] + bs[1 * H_ + col];
                    float gg_ = gg[e] + bs[2 * H_ + col];
                    float go_ = go[e] + bs[3 * H_ + col];
                    float cn = sigm(gf_) * cv[e] + sigm(gi_) * tanhf(gg_);
                    cv[e] = cn;
                    hv[e] = (__bf16)(sigm(go_) * tanhf(cn));
                }
                *(f32x4*)&s_c[r * 16 + hq * 4] = cv;
                __bf16* hdst = g_h[(p + 1) & 1] + L * B_ * H_ + r * H_ + hc0 + hq * 4;
                *(uint2*)hdst = *(const uint2*)hv;
            }
            gridbar(p + 1);
        }
    } else {
        // ================= DEC BLOCK =================
        const int db = bid - NCELL;
        const int ntile = db % 11, mh = db / 11;
        const int kk = wid >> 2;
        const int mw = wid & 3;
        const int col = ntile * 16 + rlo;
        const int colc = (col < OUTF_) ? col : (OUTF_ - 1);

        auto decwork = [&](int t, bool winf) {
            const __bf16* h2 = g_h[(t + 1) & 1] + 2 * B_ * H_;
            const __bf16* pa = h2 + (mh * 64 + mw * 16 + rlo) * H_ + kk * 512 + khi * 8;
            const __bf16* pb = g_Wdec + (long)colc * H_ + kk * 512 + khi * 8;
            f32x4 acc = {};
            bf16x8 a0, a1, b0, b1, c0, c1, d0, d1;
            a0 = ld8(pa); a1 = ld8(pa + 32); b0 = ld8(pb); b1 = ld8(pb + 32);
            c0 = ld8(pa + 64); c1 = ld8(pa + 96); d0 = ld8(pb + 64); d1 = ld8(pb + 96);
            for (int i = 0; i < 8; i += 2) {
                acc = mfma_bf16(a0, b0, acc);
                acc = mfma_bf16(a1, b1, acc);
                if (i + 2 < 8) {
                    int k = (i + 2) << 6;
                    a0 = ld8(pa + k); a1 = ld8(pa + k + 32);
                    b0 = ld8(pb + k); b1 = ld8(pb + k + 32);
                }
                acc = mfma_bf16(c0, d0, acc);
                acc = mfma_bf16(c1, d1, acc);
                if (i + 3 < 8) {
                    int k = (i + 3) << 6;
                    c0 = ld8(pa + k); c1 = ld8(pa + k + 32);
                    d0 = ld8(pb + k); d1 = ld8(pb + k + 32);
                }
            }
            if (kk == 1) {
#pragma unroll
                for (int j = 0; j < 4; ++j)
                    s_acc[(mw * 16 + khi * 4 + j) * 16 + rlo] = acc[j];
            }
            __syncthreads();
            if (kk == 0) {
#pragma unroll
                for (int j = 0; j < 4; ++j)
                    acc[j] += s_acc[(mw * 16 + khi * 4 + j) * 16 + rlo];
                if (col < OUTF_) {
                    const float bias = g_bdec[col];
                    const bool gt = (((t + 1) % 10) < 5);
#pragma unroll
                    for (int j = 0; j < 4; ++j) {
                        int row = mh * 64 + mw * 16 + khi * 4 + j;
                        float ov = acc[j] + bias;
                        long oidx = (long)row * (T_ * OUTF_) + (long)t * OUTF_ + col;
                        if (f32o) ((float*)dout)[oidx] = ov;
                        else ((__bf16*)dout)[oidx] = (__bf16)ov;
                        if (winf) {
                            float nxt = gt ? rdf(xseq, (long)row * (T_ * INF_) + (long)(t + 1) * INF_ + col, f32o)
                                           : ov;
                            g_infp[row * INFP_ + col] = (__bf16)nxt;
                        }
                    }
                }
            }
            __syncthreads();
            if (tid == 0) {
                __threadfence();
                __hip_atomic_fetch_add(&g_dflag, 1, __ATOMIC_RELEASE, __HIP_MEMORY_SCOPE_AGENT);
            }
        };

        for (int p = 0; p < T_; ++p) {
            if (p >= 1) decwork(p - 1, true);
            gridbar(p + 1);
        }
        decwork(T_ - 1, false);
    }
}

extern "C" void kernel_launch(void* const* d_in, const int* in_sizes, int n_in,
                              void* d_out, int out_size, void* d_ws, size_t ws_size,
                              hipStream_t stream) {
    const void* xseq = d_in[0];
    detect_k<<<1, 256, 0, stream>>>((const unsigned int*)xseq);
    prep_k<<<2048, 256, 0, stream>>>(d_in[1], d_in[2], d_in[5], d_in[6], d_in[9],
                                     d_in[10], d_in[13], d_in[3], d_in[4], d_in[7],
                                     d_in[8], d_in[11], d_in[12], d_in[14], xseq);
    persist_k<<<NBLK, 512, 0, stream>>>(xseq, d_out);
}

// Round 9
// 14901.694 us; speedup vs baseline: 1.3025x; 1.1916x over previous
//
#include <hip/hip_runtime.h>

#define B_ 128
#define T_ 200
#define INF_ 175
#define INFP_ 192
#define H_ 1024
#define G4_ 4096
#define OUTF_ 175
#define BH3_ (3 * B_ * H_)
#define NCELL 192
#define NDEC 22
#define NWORK (NCELL + NDEC)   // 214 worker blocks
#define NBLK (NWORK + 1)       // + 1 master block

typedef __bf16 bf16x8 __attribute__((ext_vector_type(8)));
typedef float f32x4 __attribute__((ext_vector_type(4)));

// ---- persistent device state ----
__device__ __attribute__((aligned(16))) __bf16 g_Wih1p[G4_ * INFP_];
__device__ __attribute__((aligned(16))) __bf16 g_Whh1[G4_ * H_];
__device__ __attribute__((aligned(16))) __bf16 g_Wih2[G4_ * H_];
__device__ __attribute__((aligned(16))) __bf16 g_Whh2[G4_ * H_];
__device__ __attribute__((aligned(16))) __bf16 g_Wih3[G4_ * H_];
__device__ __attribute__((aligned(16))) __bf16 g_Whh3[G4_ * H_];
__device__ __attribute__((aligned(16))) __bf16 g_Wdec[OUTF_ * H_];
__device__ float g_bsum[3 * G4_];
__device__ float g_bdec[OUTF_];
__device__ __attribute__((aligned(16))) __bf16 g_h[2][BH3_];
__device__ __attribute__((aligned(16))) __bf16 g_infp[B_ * INFP_];
__device__ int g_isf32;
// ---- sync state (monotonic within a launch; reset by prep_k) ----
__device__ int g_flags[256];    // per-worker arrival flags (relaxed stores)
__device__ int g_dflags[32];    // per-dec-block infp-ready flags
__device__ int g_gen8[128];     // 8 broadcast generation words, 64B apart
__device__ int g_iready;        // master-aggregated infp-ready step

__device__ __forceinline__ f32x4 mfma_bf16(bf16x8 a, bf16x8 b, f32x4 c) {
    return __builtin_amdgcn_mfma_f32_16x16x32_bf16(a, b, c, 0, 0, 0);
}
__device__ __forceinline__ bf16x8 ld8(const __bf16* p) {
    return *reinterpret_cast<const bf16x8*>(p);
}
__device__ __forceinline__ float sigm(float x) { return 1.f / (1.f + expf(-x)); }
__device__ __forceinline__ float rdf(const void* p, long i, int f32) {
    return f32 ? ((const float*)p)[i] : (float)((const __bf16*)p)[i];
}
__device__ __forceinline__ unsigned short bf2u(__bf16 v) {
    union { __bf16 b; unsigned short u; } c; c.b = v; return c.u;
}

// bounded relaxed spin + one acquire at exit. Bounds sized so even a fully
// broken barrier finishes the kernel in <0.5s total (no watchdog kill).
__device__ __forceinline__ void spin_ge(int* addr, int target, int iters) {
    for (int it = 0; it < iters; ++it) {
        if (__hip_atomic_load(addr, __ATOMIC_RELAXED, __HIP_MEMORY_SCOPE_AGENT) >= target)
            break;
        __builtin_amdgcn_s_sleep(2);
    }
    (void)__hip_atomic_load(addr, __ATOMIC_ACQUIRE, __HIP_MEMORY_SCOPE_AGENT);
}

// ---- dtype probe ----
__global__ void detect_k(const unsigned int* __restrict__ xw) {
    __shared__ int cnt;
    if (threadIdx.x == 0) cnt = 0;
    __syncthreads();
    unsigned int w = xw[threadIdx.x];
    int e = (w >> 7) & 0xFF;
    if (e >= 140) atomicAdd(&cnt, 1);
    __syncthreads();
    if (threadIdx.x == 0) g_isf32 = (cnt >= 16) ? 1 : 0;
}

// ---- prep: weights->bf16, bias sums, zero state, infp(0), reset ALL sync ----
__global__ void prep_k(const void* Wih1, const void* Whh1, const void* Wih2,
                       const void* Whh2, const void* Wih3, const void* Whh3,
                       const void* Wdec, const void* bih1, const void* bhh1,
                       const void* bih2, const void* bhh2, const void* bih3,
                       const void* bhh3, const void* bdec, const void* xseq) {
    const int f = g_isf32;
    const int idx = blockIdx.x * 256 + threadIdx.x;
    const int stride = gridDim.x * 256;
    if (idx < 256) g_flags[idx] = 0;
    if (idx < 32) g_dflags[idx] = 0;
    if (idx < 128) g_gen8[idx] = 0;
    if (idx == 0) g_iready = 0;
    for (int i = idx; i < G4_ * INFP_; i += stride) {
        int n = i / INFP_, k = i - n * INFP_;
        g_Wih1p[i] = (k < INF_) ? (__bf16)rdf(Wih1, (long)n * INF_ + k, f) : (__bf16)0.f;
    }
    for (int i = idx; i < G4_ * H_; i += stride) {
        g_Whh1[i] = (__bf16)rdf(Whh1, i, f);
        g_Wih2[i] = (__bf16)rdf(Wih2, i, f);
        g_Whh2[i] = (__bf16)rdf(Whh2, i, f);
        g_Wih3[i] = (__bf16)rdf(Wih3, i, f);
        g_Whh3[i] = (__bf16)rdf(Whh3, i, f);
    }
    for (int i = idx; i < OUTF_ * H_; i += stride) g_Wdec[i] = (__bf16)rdf(Wdec, i, f);
    for (int i = idx; i < G4_; i += stride) {
        g_bsum[i]           = rdf(bih1, i, f) + rdf(bhh1, i, f);
        g_bsum[G4_ + i]     = rdf(bih2, i, f) + rdf(bhh2, i, f);
        g_bsum[2 * G4_ + i] = rdf(bih3, i, f) + rdf(bhh3, i, f);
    }
    for (int i = idx; i < OUTF_; i += stride) g_bdec[i] = rdf(bdec, i, f);
    for (int i = idx; i < 2 * BH3_; i += stride) (&g_h[0][0])[i] = (__bf16)0.f;
    for (int i = idx; i < B_ * INFP_; i += stride) {
        int b = i / INFP_, k = i - b * INFP_;
        g_infp[i] = (k < INF_) ? (__bf16)rdf(xseq, (long)b * (T_ * INF_) + k, f) : (__bf16)0.f;
    }
}

// ---- worker side of the barrier: RMW-free arrival, per-group gen poll ----
__device__ __forceinline__ void gridbar_w(int bid, int grp, int target) {
    __syncthreads();   // drains each wave's vmcnt (all nt stores complete)
    if (threadIdx.x == 0) {
        __threadfence();  // visibility of this block's stores before arrival
        __hip_atomic_store(&g_flags[bid], target, __ATOMIC_RELAXED, __HIP_MEMORY_SCOPE_AGENT);
        spin_ge(&g_gen8[grp * 16], target, 50000);
    }
    __syncthreads();
}

// depth-2 register-pipelined GEMM over NCH k-chunks for m-frags [BASE,BASE+4)
template <int NCH, int BASE>
__device__ __forceinline__ void gemm_half(const __bf16* const (&ap)[8],
                                          const bf16x8 (&wreg)[32],
                                          f32x4 (&acc)[8]) {
    bf16x8 a0[4], a1[4];
#pragma unroll
    for (int mf = 0; mf < 4; ++mf) a0[mf] = ld8(ap[BASE + mf]);
    if (NCH > 1) {
#pragma unroll
        for (int mf = 0; mf < 4; ++mf) a1[mf] = ld8(ap[BASE + mf] + 32);
    }
#pragma unroll
    for (int c = 0; c < NCH; c += 2) {
#pragma unroll
        for (int mf = 0; mf < 4; ++mf)
            acc[BASE + mf] = mfma_bf16(a0[mf], wreg[c], acc[BASE + mf]);
        if (c + 2 < NCH) {
#pragma unroll
            for (int mf = 0; mf < 4; ++mf) a0[mf] = ld8(ap[BASE + mf] + (c + 2) * 32);
        }
        if (c + 1 < NCH) {
#pragma unroll
            for (int mf = 0; mf < 4; ++mf)
                acc[BASE + mf] = mfma_bf16(a1[mf], wreg[c + 1], acc[BASE + mf]);
            if (c + 3 < NCH) {
#pragma unroll
                for (int mf = 0; mf < 4; ++mf) a1[mf] = ld8(ap[BASE + mf] + (c + 3) * 32);
            }
        }
    }
}

// ---- persistent kernel ----
__global__ __launch_bounds__(512, 1) void persist_k(const void* __restrict__ xseq,
                                                    void* __restrict__ dout) {
    __shared__ float s_acc[B_ * 4 * 16];  // 32KB
    __shared__ float s_c[B_ * 16];        // 8KB
    __shared__ int s_nf, s_nd;
    const int bid = blockIdx.x;
    const int grp = bid & 7;
    const int tid = threadIdx.x;
    const int lane = tid & 63;
    const int wid = tid >> 6;
    const int rlo = lane & 15, khi = lane >> 4;
    const int f32o = g_isf32;

    if (bid < NCELL) {
        // ================= CELL BLOCK =================
        const int L = bid >> 6;
        const int hc0 = (bid & 63) << 4;
        const int op = wid >> 2;         // 0: x-GEMM, 1: recurrent GEMM
        const int g = wid & 3;           // gate
        const float* bs = g_bsum + L * G4_;

        const __bf16* Bm; int K;
        if (op == 0) {
            if (L == 0) { Bm = g_Wih1p; K = INFP_; }
            else        { Bm = (L == 1) ? g_Wih2 : g_Wih3; K = H_; }
        } else {
            Bm = (L == 0) ? g_Whh1 : (L == 1) ? g_Whh2 : g_Whh3; K = H_;
        }
        const __bf16* wp = Bm + (long)(g * H_ + hc0 + rlo) * K + khi * 8;
        bf16x8 wreg[32];
        if (K == INFP_) {
#pragma unroll
            for (int c = 0; c < 6; ++c) wreg[c] = ld8(wp + c * 32);
        } else {
#pragma unroll
            for (int c = 0; c < 32; ++c) wreg[c] = ld8(wp + c * 32);
        }

        for (int i = tid; i < B_ * 16; i += 512) s_c[i] = 0.f;

        for (int p = 0; p < T_; ++p) {
            const __bf16* hin = g_h[p & 1];
            const __bf16* Ap; int sA;
            if (op == 0) {
                if (L == 0) { Ap = g_infp; sA = INFP_; }
                else        { Ap = hin + (L - 1) * B_ * H_; sA = H_; }
            } else { Ap = hin + L * B_ * H_; sA = H_; }

            // L0 x-waves wait for this step's in_frame readiness
            if (L == 0 && op == 0 && p > 0) {
                if (lane == 0) spin_ge(&g_iready, p, 30000);
            }

            const __bf16* ap[8];
#pragma unroll
            for (int mf = 0; mf < 8; ++mf)
                ap[mf] = Ap + (mf * 16 + rlo) * sA + khi * 8;

            f32x4 acc[8] = {};
            if (K == INFP_) {
                gemm_half<6, 0>(ap, wreg, acc);
                gemm_half<6, 4>(ap, wreg, acc);
            } else {
                gemm_half<32, 0>(ap, wreg, acc);
                gemm_half<32, 4>(ap, wreg, acc);
            }

            if (op == 1) {
#pragma unroll
                for (int mf = 0; mf < 8; ++mf)
#pragma unroll
                    for (int j = 0; j < 4; ++j) {
                        int r = mf * 16 + khi * 4 + j;
                        s_acc[(r * 4 + g) * 16 + rlo] = acc[mf][j];
                    }
            }
            __syncthreads();
            if (op == 0) {
#pragma unroll
                for (int mf = 0; mf < 8; ++mf)
#pragma unroll
                    for (int j = 0; j < 4; ++j) {
                        int r = mf * 16 + khi * 4 + j;
                        s_acc[(r * 4 + g) * 16 + rlo] += acc[mf][j];
                    }
            }
            __syncthreads();

            // epilogue: 8 waves x 16 rows, 4 cols/lane; h out = nontemporal store
            {
                const int r = wid * 16 + rlo;
                const int hq = khi;
                f32x4 ga = *(const f32x4*)&s_acc[(r * 4 + 0) * 16 + hq * 4];
                f32x4 gf = *(const f32x4*)&s_acc[(r * 4 + 1) * 16 + hq * 4];
                f32x4 gg = *(const f32x4*)&s_acc[(r * 4 + 2) * 16 + hq * 4];
                f32x4 go = *(const f32x4*)&s_acc[(r * 4 + 3) * 16 + hq * 4];
                f32x4 cv = *(const f32x4*)&s_c[r * 16 + hq * 4];
                unsigned long long hbits;
                unsigned short* hp = (unsigned short*)&hbits;
#pragma unroll
                for (int e = 0; e < 4; ++e) {
                    int col = hc0 + hq * 4 + e;
                    float gi_ = ga[e] + bs[0 * H_ + col];
                    float gf_ = gf[e] + bs[1 * H_ + col];
                    float gg_ = gg[e] + bs[2 * H_ + col];
                    float go_ = go[e] + bs[3 * H_ + col];
                    float cn = sigm(gf_) * cv[e] + sigm(gi_) * tanhf(gg_);
                    cv[e] = cn;
                    hp[e] = bf2u((__bf16)(sigm(go_) * tanhf(cn)));
                }
                *(f32x4*)&s_c[r * 16 + hq * 4] = cv;
                __bf16* hdst = g_h[(p + 1) & 1] + L * B_ * H_ + r * H_ + hc0 + hq * 4;
                __builtin_nontemporal_store(hbits, (unsigned long long*)hdst);
            }
            gridbar_w(bid, grp, p + 1);
        }
    } else if (bid < NWORK) {
        // ================= DEC BLOCK =================
        const int db = bid - NCELL;
        const int ntile = db % 11, mh = db / 11;
        const int kk = wid >> 2;
        const int mw = wid & 3;
        const int col = ntile * 16 + rlo;
        const int colc = (col < OUTF_) ? col : (OUTF_ - 1);

        auto decwork = [&](int t, bool winf) {
            const bool gt = (((t + 1) % 10) < 5);
            // gt fast-path: infp(t+1) from xseq, independent of this GEMM
            if (winf && gt) {
                if (kk == 0 && col < OUTF_) {
#pragma unroll
                    for (int j = 0; j < 4; ++j) {
                        int row = mh * 64 + mw * 16 + khi * 4 + j;
                        float nxt = rdf(xseq, (long)row * (T_ * INF_) + (long)(t + 1) * INF_ + col, f32o);
                        __builtin_nontemporal_store(bf2u((__bf16)nxt),
                            (unsigned short*)g_infp + row * INFP_ + col);
                    }
                }
                __syncthreads();
                if (tid == 0) {
                    __threadfence();
                    __hip_atomic_store(&g_dflags[db], t + 1, __ATOMIC_RELAXED, __HIP_MEMORY_SCOPE_AGENT);
                }
            }
            const __bf16* h2 = g_h[(t + 1) & 1] + 2 * B_ * H_;
            const __bf16* pa = h2 + (mh * 64 + mw * 16 + rlo) * H_ + kk * 512 + khi * 8;
            const __bf16* pb = g_Wdec + (long)colc * H_ + kk * 512 + khi * 8;
            f32x4 acc = {};
            bf16x8 a0, a1, b0, b1, c0, c1, d0, d1;
            a0 = ld8(pa); a1 = ld8(pa + 32); b0 = ld8(pb); b1 = ld8(pb + 32);
            c0 = ld8(pa + 64); c1 = ld8(pa + 96); d0 = ld8(pb + 64); d1 = ld8(pb + 96);
            for (int i = 0; i < 8; i += 2) {
                acc = mfma_bf16(a0, b0, acc);
                acc = mfma_bf16(a1, b1, acc);
                if (i + 2 < 8) {
                    int k = (i + 2) << 6;
                    a0 = ld8(pa + k); a1 = ld8(pa + k + 32);
                    b0 = ld8(pb + k); b1 = ld8(pb + k + 32);
                }
                acc = mfma_bf16(c0, d0, acc);
                acc = mfma_bf16(c1, d1, acc);
                if (i + 3 < 8) {
                    int k = (i + 3) << 6;
                    c0 = ld8(pa + k); c1 = ld8(pa + k + 32);
                    d0 = ld8(pb + k); d1 = ld8(pb + k + 32);
                }
            }
            if (kk == 1) {
#pragma unroll
                for (int j = 0; j < 4; ++j)
                    s_acc[(mw * 16 + khi * 4 + j) * 16 + rlo] = acc[j];
            }
            __syncthreads();
            if (kk == 0) {
#pragma unroll
                for (int j = 0; j < 4; ++j)
                    acc[j] += s_acc[(mw * 16 + khi * 4 + j) * 16 + rlo];
                if (col < OUTF_) {
                    const float bias = g_bdec[col];
#pragma unroll
                    for (int j = 0; j < 4; ++j) {
                        int row = mh * 64 + mw * 16 + khi * 4 + j;
                        float ov = acc[j] + bias;
                        long oidx = (long)row * (T_ * OUTF_) + (long)t * OUTF_ + col;
                        if (f32o) __builtin_nontemporal_store(ov, (float*)dout + oidx);
                        else __builtin_nontemporal_store(bf2u((__bf16)ov), (unsigned short*)dout + oidx);
                        if (winf && !gt) {
                            __builtin_nontemporal_store(bf2u((__bf16)ov),
                                (unsigned short*)g_infp + row * INFP_ + col);
                        }
                    }
                }
            }
            __syncthreads();
            if (winf && !gt && tid == 0) {
                __threadfence();
                __hip_atomic_store(&g_dflags[db], t + 1, __ATOMIC_RELAXED, __HIP_MEMORY_SCOPE_AGENT);
            }
        };

        for (int p = 0; p < T_; ++p) {
            if (p >= 1) decwork(p - 1, true);
            gridbar_w(bid, grp, p + 1);
        }
        decwork(T_ - 1, false);
    } else {
        // ======== MASTER BLOCK (barrier + iready aggregation) ========
        for (int p = 0; p < T_; ++p) {
            const int tgt = p + 1;
            bool ir_done = false;
            for (int it = 0; it < 30000; ++it) {
                if (tid == 0) { s_nf = 0; s_nd = 0; }
                __syncthreads();
                int bad_f = 0, bad_d = 0;
                if (tid < NWORK)
                    bad_f = (__hip_atomic_load(&g_flags[tid], __ATOMIC_RELAXED, __HIP_MEMORY_SCOPE_AGENT) < tgt);
                if (!ir_done && tid < NDEC)
                    bad_d = (__hip_atomic_load(&g_dflags[tid], __ATOMIC_RELAXED, __HIP_MEMORY_SCOPE_AGENT) < p);
                if (bad_f) s_nf = 1;
                if (bad_d) s_nd = 1;
                __syncthreads();
                if (!ir_done && !s_nd) {
                    if (tid == 0)
                        __hip_atomic_store(&g_iready, p, __ATOMIC_RELAXED, __HIP_MEMORY_SCOPE_AGENT);
                    ir_done = true;
                }
                if (!s_nf) break;
                __builtin_amdgcn_s_sleep(1);
            }
            // FIX (round-8 livelock): all flags arrived => dec work for step p is
            // done (dflag stores precede flag stores), so publishing is safe even
            // if the same-iteration dflag check raced and never cleared s_nd.
            if (!ir_done && tid == 0)
                __hip_atomic_store(&g_iready, p, __ATOMIC_RELAXED, __HIP_MEMORY_SCOPE_AGENT);
            __syncthreads();
            if (tid < 8)
                __hip_atomic_store(&g_gen8[tid * 16], tgt, __ATOMIC_RELAXED, __HIP_MEMORY_SCOPE_AGENT);
        }
    }
}

extern "C" void kernel_launch(void* const* d_in, const int* in_sizes, int n_in,
                              void* d_out, int out_size, void* d_ws, size_t ws_size,
                              hipStream_t stream) {
    const void* xseq = d_in[0];
    detect_k<<<1, 256, 0, stream>>>((const unsigned int*)xseq);
    prep_k<<<2048, 256, 0, stream>>>(d_in[1], d_in[2], d_in[5], d_in[6], d_in[9],
                                     d_in[10], d_in[13], d_in[3], d_in[4], d_in[7],
                                     d_in[8], d_in[11], d_in[12], d_in[14], xseq);
    persist_k<<<NBLK, 512, 0, stream>>>(xseq, d_out);
}